// Round 1
// baseline (205.885 us; speedup 1.0000x reference)
//
#include <hip/hip_runtime.h>
#include <math.h>

#define H 1024
#define S 32768

// ws layout (floats):
// [0,1024)     v = W^T @ hidden
// [1024,2048)  per-block max partials (K2 grid = 1024 blocks)
// [2048,3072)  per-block sumexp partials
// [3072,3074)  M, invSum
// energies live in d_out (finalized in-place by K4)

// K1: v[h] = sum_d W[d*H+h] * hidden[d].
// grid (4, 64): x = column group of 256, y = d-group of 16 rows.
__global__ __launch_bounds__(256) void compute_v(const float* __restrict__ W,
                                                 const float* __restrict__ hidden,
                                                 float* __restrict__ v) {
    int h = blockIdx.x * 256 + threadIdx.x;
    int d0 = blockIdx.y * 16;
    float acc = 0.f;
#pragma unroll
    for (int j = 0; j < 16; ++j) {
        int d = d0 + j;
        acc += W[(size_t)d * H + h] * hidden[d];  // coalesced across lanes
    }
    atomicAdd(&v[h], acc);
}

// K2: energies[s] = enc[s,:] . v ; per-block online-softmax partials.
// One wave per row; v kept in 16 registers per lane. 4 waves/block, 8 rows/wave
// -> 32 rows/block, grid = S/32 = 1024.
__global__ __launch_bounds__(256) void energies_kernel(const float* __restrict__ enc,
                                                       const float* __restrict__ v,
                                                       float* __restrict__ energies,
                                                       float* __restrict__ pmax,
                                                       float* __restrict__ psum) {
    const int lane = threadIdx.x & 63;
    const int wave = threadIdx.x >> 6;

    const float4* v4 = (const float4*)v;
    float4 va = v4[lane];
    float4 vb = v4[64 + lane];
    float4 vc = v4[128 + lane];
    float4 vd = v4[192 + lane];

    float m = -INFINITY;
    float sum = 0.f;

    int s0 = blockIdx.x * 32 + wave * 8;
#pragma unroll 1
    for (int r = 0; r < 8; ++r) {
        int s = s0 + r;
        const float4* row = (const float4*)(enc + (size_t)s * H);
        float4 a = row[lane];
        float4 b = row[64 + lane];
        float4 c = row[128 + lane];
        float4 d = row[192 + lane];
        float dot = a.x * va.x + a.y * va.y + a.z * va.z + a.w * va.w;
        dot += b.x * vb.x + b.y * vb.y + b.z * vb.z + b.w * vb.w;
        dot += c.x * vc.x + c.y * vc.y + c.z * vc.z + c.w * vc.w;
        dot += d.x * vd.x + d.y * vd.y + d.z * vd.z + d.w * vd.w;
        // full-wave butterfly reduce (all 64 lanes end with the sum)
#pragma unroll
        for (int off = 32; off > 0; off >>= 1) dot += __shfl_xor(dot, off, 64);
        if (lane == 0) energies[s] = dot;
        float mnew = fmaxf(m, dot);
        sum = sum * __expf(m - mnew) + __expf(dot - mnew);
        m = mnew;
    }

    __shared__ float wm[4], wsum[4];
    if (lane == 0) { wm[wave] = m; wsum[wave] = sum; }
    __syncthreads();
    if (threadIdx.x == 0) {
        float M = wm[0], Sm = wsum[0];
#pragma unroll
        for (int w = 1; w < 4; ++w) {
            float Mn = fmaxf(M, wm[w]);
            Sm = Sm * __expf(M - Mn) + wsum[w] * __expf(wm[w] - Mn);
            M = Mn;
        }
        pmax[blockIdx.x] = M;
        psum[blockIdx.x] = Sm;
    }
}

// K3: combine 1024 block partials -> M, invSum. Single block of 1024.
__global__ __launch_bounds__(1024) void combine(const float* __restrict__ pmax,
                                                const float* __restrict__ psum,
                                                float* __restrict__ MS) {
    int tid = threadIdx.x;
    float m = pmax[tid];
    float s = psum[tid];
    __shared__ float sm[1024];
    __shared__ float ss[1024];
    sm[tid] = m;
    __syncthreads();
    for (int off = 512; off > 0; off >>= 1) {
        if (tid < off) sm[tid] = fmaxf(sm[tid], sm[tid + off]);
        __syncthreads();
    }
    float M = sm[0];
    ss[tid] = s * __expf(m - M);
    __syncthreads();
    for (int off = 512; off > 0; off >>= 1) {
        if (tid < off) ss[tid] += ss[tid + off];
        __syncthreads();
    }
    if (tid == 0) {
        MS[0] = M;
        MS[1] = 1.0f / ss[0];
    }
}

// K4: out[i] = exp(e[i]-M) * invSum, in-place on d_out, float4.
__global__ __launch_bounds__(256) void finalize(float* __restrict__ out,
                                                const float* __restrict__ MS) {
    int i = blockIdx.x * 256 + threadIdx.x;
    float M = MS[0];
    float inv = MS[1];
    float4 e = ((const float4*)out)[i];
    float4 o;
    o.x = __expf(e.x - M) * inv;
    o.y = __expf(e.y - M) * inv;
    o.z = __expf(e.z - M) * inv;
    o.w = __expf(e.w - M) * inv;
    ((float4*)out)[i] = o;
}

extern "C" void kernel_launch(void* const* d_in, const int* in_sizes, int n_in,
                              void* d_out, int out_size, void* d_ws, size_t ws_size,
                              hipStream_t stream) {
    const float* hidden = (const float*)d_in[0];   // [H]
    const float* enc    = (const float*)d_in[1];   // [S,H]
    const float* W      = (const float*)d_in[2];   // [H,H]
    // d_in[3] = b: softmax is shift-invariant -> b contributes a constant, skip it.

    float* ws   = (float*)d_ws;
    float* v    = ws;          // 1024
    float* pmax = ws + 1024;   // 1024
    float* psum = ws + 2048;   // 1024
    float* MS   = ws + 3072;   // 2
    float* out  = (float*)d_out;  // energies scratch, then probabilities

    hipMemsetAsync(v, 0, H * sizeof(float), stream);
    compute_v<<<dim3(4, 64), 256, 0, stream>>>(W, hidden, v);
    energies_kernel<<<S / 32, 256, 0, stream>>>(enc, v, out, pmax, psum);
    combine<<<1, 1024, 0, stream>>>(pmax, psum, MS);
    finalize<<<S / 4 / 256, 256, 0, stream>>>(out, MS);
}

// Round 2
// 203.510 us; speedup vs baseline: 1.0117x; 1.0117x over previous
//
#include <hip/hip_runtime.h>
#include <math.h>

#define H 1024
#define S 32768

// ws layout (floats):
// [0,1024)      v = W^T @ hidden
// [1024,3072)   per-block max partials (K2 grid = 2048 blocks)
// [3072,5120)   per-block sumexp partials
// [5120,5122)   M, invSum
// energies live in d_out (finalized in-place by K4)

// K1: v[h] = sum_d W[d*H+h] * hidden[d].
// grid (4, 64): x = column group of 256, y = d-group of 16 rows.
__global__ __launch_bounds__(256) void compute_v(const float* __restrict__ W,
                                                 const float* __restrict__ hidden,
                                                 float* __restrict__ v) {
    int h = blockIdx.x * 256 + threadIdx.x;
    int d0 = blockIdx.y * 16;
    float acc = 0.f;
#pragma unroll
    for (int j = 0; j < 16; ++j) {
        int d = d0 + j;
        acc += W[(size_t)d * H + h] * hidden[d];  // coalesced across lanes
    }
    atomicAdd(&v[h], acc);
}

// K2: energies[s] = enc[s,:] . v ; per-block (max, sumexp) partials.
// 4 waves/block, 4 rows/wave -> 16 rows/block, grid = S/16 = 2048.
// Fully unrolled: all 16 row-loads issue before the reduces; butterflies for
// the 4 rows interleave for ILP; no online rescale in the hot path.
__global__ __launch_bounds__(256) void energies_kernel(const float* __restrict__ enc,
                                                       const float* __restrict__ v,
                                                       float* __restrict__ energies,
                                                       float* __restrict__ pmax,
                                                       float* __restrict__ psum) {
    const int lane = threadIdx.x & 63;
    const int wave = threadIdx.x >> 6;

    const float4* v4 = (const float4*)v;
    float4 va = v4[lane];
    float4 vb = v4[64 + lane];
    float4 vc = v4[128 + lane];
    float4 vd = v4[192 + lane];

    const int s0 = blockIdx.x * 16 + wave * 4;
    const float4* base = (const float4*)(enc + (size_t)s0 * H);

    float dot[4];
#pragma unroll
    for (int r = 0; r < 4; ++r) {
        const float4* row = base + r * (H / 4);
        float4 a = row[lane];
        float4 b = row[64 + lane];
        float4 c = row[128 + lane];
        float4 d = row[192 + lane];
        float t = a.x * va.x + a.y * va.y + a.z * va.z + a.w * va.w;
        t += b.x * vb.x + b.y * vb.y + b.z * vb.z + b.w * vb.w;
        t += c.x * vc.x + c.y * vc.y + c.z * vc.z + c.w * vc.w;
        t += d.x * vd.x + d.y * vd.y + d.z * vd.z + d.w * vd.w;
        dot[r] = t;
    }

    // 4 interleaved butterfly reductions (all lanes end with full sums)
#pragma unroll
    for (int off = 32; off > 0; off >>= 1) {
#pragma unroll
        for (int r = 0; r < 4; ++r) dot[r] += __shfl_xor(dot[r], off, 64);
    }

    if (lane == 0) {
        float4 e = make_float4(dot[0], dot[1], dot[2], dot[3]);
        *(float4*)(energies + s0) = e;
    }

    float m = fmaxf(fmaxf(dot[0], dot[1]), fmaxf(dot[2], dot[3]));
    float sum = __expf(dot[0] - m) + __expf(dot[1] - m) +
                __expf(dot[2] - m) + __expf(dot[3] - m);

    __shared__ float wm[4], wsum[4];
    if (lane == 0) { wm[wave] = m; wsum[wave] = sum; }
    __syncthreads();
    if (threadIdx.x == 0) {
        float M = wm[0], Sm = wsum[0];
#pragma unroll
        for (int w = 1; w < 4; ++w) {
            float Mn = fmaxf(M, wm[w]);
            Sm = Sm * __expf(M - Mn) + wsum[w] * __expf(wm[w] - Mn);
            M = Mn;
        }
        pmax[blockIdx.x] = M;
        psum[blockIdx.x] = Sm;
    }
}

// K3: combine 2048 block partials -> M, invSum. Single block of 1024,
// shuffle-based (2 sync points).
__global__ __launch_bounds__(1024) void combine(const float* __restrict__ pmax,
                                                const float* __restrict__ psum,
                                                float* __restrict__ MS) {
    const int tid = threadIdx.x;
    const int lane = tid & 63;
    const int wave = tid >> 6;

    float m1 = pmax[tid], s1 = psum[tid];
    float m2 = pmax[tid + 1024], s2 = psum[tid + 1024];
    float M = fmaxf(m1, m2);
    float Sv = s1 * __expf(m1 - M) + s2 * __expf(m2 - M);

#pragma unroll
    for (int off = 32; off > 0; off >>= 1) {
        float Mo = __shfl_xor(M, off, 64);
        float So = __shfl_xor(Sv, off, 64);
        float Mn = fmaxf(M, Mo);
        Sv = Sv * __expf(M - Mn) + So * __expf(Mo - Mn);
        M = Mn;
    }

    __shared__ float sm[16], ss[16];
    if (lane == 0) { sm[wave] = M; ss[wave] = Sv; }
    __syncthreads();
    if (wave == 0) {
        float Mv = (lane < 16) ? sm[lane] : -INFINITY;
        float Sw = (lane < 16) ? ss[lane] : 0.f;
#pragma unroll
        for (int off = 8; off > 0; off >>= 1) {
            float Mo = __shfl_xor(Mv, off, 64);
            float So = __shfl_xor(Sw, off, 64);
            float Mn = fmaxf(Mv, Mo);
            Sw = Sw * __expf(Mv - Mn) + So * __expf(Mo - Mn);
            Mv = Mn;
        }
        if (lane == 0) {
            MS[0] = Mv;
            MS[1] = 1.0f / Sw;
        }
    }
}

// K4: out[i] = exp(e[i]-M) * invSum, in-place on d_out, float4.
__global__ __launch_bounds__(256) void finalize(float* __restrict__ out,
                                                const float* __restrict__ MS) {
    int i = blockIdx.x * 256 + threadIdx.x;
    float M = MS[0];
    float inv = MS[1];
    float4 e = ((const float4*)out)[i];
    float4 o;
    o.x = __expf(e.x - M) * inv;
    o.y = __expf(e.y - M) * inv;
    o.z = __expf(e.z - M) * inv;
    o.w = __expf(e.w - M) * inv;
    ((float4*)out)[i] = o;
}

extern "C" void kernel_launch(void* const* d_in, const int* in_sizes, int n_in,
                              void* d_out, int out_size, void* d_ws, size_t ws_size,
                              hipStream_t stream) {
    const float* hidden = (const float*)d_in[0];   // [H]
    const float* enc    = (const float*)d_in[1];   // [S,H]
    const float* W      = (const float*)d_in[2];   // [H,H]
    // d_in[3] = b: softmax is shift-invariant -> b contributes a constant, skip it.

    float* ws   = (float*)d_ws;
    float* v    = ws;          // 1024
    float* pmax = ws + 1024;   // 2048
    float* psum = ws + 3072;   // 2048
    float* MS   = ws + 5120;   // 2
    float* out  = (float*)d_out;  // energies scratch, then probabilities

    hipMemsetAsync(v, 0, H * sizeof(float), stream);
    compute_v<<<dim3(4, 64), 256, 0, stream>>>(W, hidden, v);
    energies_kernel<<<S / 16, 256, 0, stream>>>(enc, v, out, pmax, psum);
    combine<<<1, 1024, 0, stream>>>(pmax, psum, MS);
    finalize<<<S / 4 / 256, 256, 0, stream>>>(out, MS);
}